// Round 1
// baseline (872.930 us; speedup 1.0000x reference)
//
#include <hip/hip_runtime.h>

// Problem constants (from reference): B=128, L=1024, RNN=1024, ATT=512
#define B_   128
#define L_   1024
#define RNN_ 1024
#define ATT_ 512

// ---------------------------------------------------------------------------
// fast tanh: tanh(x) = 1 - 2/(exp(2x)+1).  __expf -> v_exp_f32, __fdividef ->
// rcp+mul. Abs error ~2e-7, far below the 4.6e-3 absmax threshold.
__device__ __forceinline__ float fast_tanh(float x) {
    float e = __expf(2.0f * x);
    return 1.0f - __fdividef(2.0f, e + 1.0f);
}

// ---------------------------------------------------------------------------
// K1: att_h[b,a] = sum_k h[b,k] * W[a,k] + bias[a]
// Tiled GEMM: block tile BM=16 (b) x BN=64 (a), K-chunks of 64. 256 threads.
// W LDS tile padded to 65 floats/row -> compute-phase reads are 2-way (free).
__global__ __launch_bounds__(256) void k1_h2att(
        const float* __restrict__ h, const float* __restrict__ W,
        const float* __restrict__ bias, float* __restrict__ att_h) {
    __shared__ float hs[16][64];       // reads are wave-uniform (broadcast)
    __shared__ float ws[64][65];       // +1 pad: bank = (a+kk)%32 -> free
    const int a0 = blockIdx.x * 64;
    const int b0 = blockIdx.y * 16;
    const int t  = threadIdx.x;
    const int a_local = t & 63;
    const int brow    = (t >> 6) * 4;  // 4 waves x 4 rows = 16 b-rows

    float acc[4] = {0.f, 0.f, 0.f, 0.f};

    for (int k0 = 0; k0 < RNN_; k0 += 64) {
        // stage h tile: 16x64 floats, one float4 per thread, coalesced
        {
            int r = t >> 4, c = (t & 15) * 4;
            const float4 v = *(const float4*)&h[(size_t)(b0 + r) * RNN_ + k0 + c];
            hs[r][c + 0] = v.x; hs[r][c + 1] = v.y;
            hs[r][c + 2] = v.z; hs[r][c + 3] = v.w;
        }
        // stage W tile: 64x64 floats, four float4 per thread, coalesced
        #pragma unroll
        for (int j = 0; j < 4; j++) {
            int r = (t >> 4) + 16 * j, c = (t & 15) * 4;
            const float4 v = *(const float4*)&W[(size_t)(a0 + r) * RNN_ + k0 + c];
            ws[r][c + 0] = v.x; ws[r][c + 1] = v.y;
            ws[r][c + 2] = v.z; ws[r][c + 3] = v.w;
        }
        __syncthreads();
        #pragma unroll 8
        for (int kk = 0; kk < 64; kk++) {
            const float wv = ws[a_local][kk];
            #pragma unroll
            for (int j = 0; j < 4; j++)
                acc[j] = fmaf(hs[brow + j][kk], wv, acc[j]);
        }
        __syncthreads();
    }
    const float bs = bias[a0 + a_local];
    #pragma unroll
    for (int j = 0; j < 4; j++)
        att_h[(size_t)(b0 + brow + j) * ATT_ + a0 + a_local] = acc[j] + bs;
}

// ---------------------------------------------------------------------------
// K2: dot[b,l] = sum_a tanh(att_feats2[b,l,a] + att_h[b,a]) * w_alpha[a] + b_alpha
// One wave per (b,l). 512 floats = 128 float4 = 2 float4/lane. Coalesced.
__global__ __launch_bounds__(256) void k2_score(
        const float* __restrict__ f2, const float* __restrict__ att_h,
        const float* __restrict__ w_alpha, const float* __restrict__ b_alpha,
        float* __restrict__ dot) {
    const int wid  = (blockIdx.x * 256 + threadIdx.x) >> 6;  // global wave id
    const int lane = threadIdx.x & 63;
    const int b = wid >> 10;
    const int l = wid & (L_ - 1);

    const float4* f  = (const float4*)f2 + (size_t)(b * L_ + l) * (ATT_ / 4);
    const float4* ah = (const float4*)att_h + (size_t)b * (ATT_ / 4);
    const float4* wa = (const float4*)w_alpha;

    float s = 0.f;
    #pragma unroll
    for (int i = 0; i < 2; i++) {
        const int idx = lane + i * 64;
        const float4 x = f[idx];
        const float4 a = ah[idx];
        const float4 w = wa[idx];
        s = fmaf(fast_tanh(x.x + a.x), w.x, s);
        s = fmaf(fast_tanh(x.y + a.y), w.y, s);
        s = fmaf(fast_tanh(x.z + a.z), w.z, s);
        s = fmaf(fast_tanh(x.w + a.w), w.w, s);
    }
    #pragma unroll
    for (int off = 32; off > 0; off >>= 1)
        s += __shfl_xor(s, off, 64);
    if (lane == 0)
        dot[b * L_ + l] = s + b_alpha[0];
}

// ---------------------------------------------------------------------------
// K3: weight[b,l] = exp(dot - max) * mask / sum(exp(dot - max) * mask)
// (softmax denominator cancels against the masked renormalization)
// One block (256 thr) per b, 4 l's per thread.
__global__ __launch_bounds__(256) void k3_softmax(
        const float* __restrict__ dot, const float* __restrict__ mask,
        float* __restrict__ weight) {
    const int b = blockIdx.x, t = threadIdx.x;
    const int base = b * L_;
    const int wv = t >> 6, lane = t & 63;
    __shared__ float sred[4];

    float v[4];
    float mx = -3.4e38f;
    #pragma unroll
    for (int j = 0; j < 4; j++) {
        v[j] = dot[base + t + 256 * j];
        mx = fmaxf(mx, v[j]);
    }
    #pragma unroll
    for (int off = 32; off > 0; off >>= 1)
        mx = fmaxf(mx, __shfl_xor(mx, off, 64));
    if (lane == 0) sred[wv] = mx;
    __syncthreads();
    mx = fmaxf(fmaxf(sred[0], sred[1]), fmaxf(sred[2], sred[3]));
    __syncthreads();

    float e[4], s = 0.f;
    #pragma unroll
    for (int j = 0; j < 4; j++) {
        e[j] = __expf(v[j] - mx) * mask[base + t + 256 * j];
        s += e[j];
    }
    #pragma unroll
    for (int off = 32; off > 0; off >>= 1)
        s += __shfl_xor(s, off, 64);
    if (lane == 0) sred[wv] = s;
    __syncthreads();
    s = sred[0] + sred[1] + sred[2] + sred[3];

    const float inv = 1.0f / s;
    #pragma unroll
    for (int j = 0; j < 4; j++)
        weight[base + t + 256 * j] = e[j] * inv;
}

// ---------------------------------------------------------------------------
// K4: out[b,d] += sum_l weight[b,l] * att_feats1[b,l,d]
// Grid (128 b, 16 l-chunks of 64), 256 threads, float4 streaming, atomic
// accumulation into zeroed d_out (16-way contention per address).
__global__ __launch_bounds__(256) void k4_wsum(
        const float* __restrict__ f1, const float* __restrict__ weight,
        float* __restrict__ out) {
    const int b = blockIdx.x, lc = blockIdx.y, t = threadIdx.x;
    const float* wrow = weight + b * L_ + lc * 64;
    const float4* base =
        (const float4*)f1 + ((size_t)b * L_ + lc * 64) * (RNN_ / 4) + t;

    float4 acc = make_float4(0.f, 0.f, 0.f, 0.f);
    #pragma unroll 8
    for (int l = 0; l < 64; l++) {
        const float w = wrow[l];
        const float4 x = base[(size_t)l * (RNN_ / 4)];
        acc.x = fmaf(w, x.x, acc.x);
        acc.y = fmaf(w, x.y, acc.y);
        acc.z = fmaf(w, x.z, acc.z);
        acc.w = fmaf(w, x.w, acc.w);
    }
    float* o = out + b * RNN_ + t * 4;
    atomicAdd(o + 0, acc.x);
    atomicAdd(o + 1, acc.y);
    atomicAdd(o + 2, acc.z);
    atomicAdd(o + 3, acc.w);
}

// ---------------------------------------------------------------------------
extern "C" void kernel_launch(void* const* d_in, const int* in_sizes, int n_in,
                              void* d_out, int out_size, void* d_ws, size_t ws_size,
                              hipStream_t stream) {
    const float* h       = (const float*)d_in[0];
    const float* f1      = (const float*)d_in[1];  // [B,L,RNN]
    const float* f2      = (const float*)d_in[2];  // [B,L,ATT]
    const float* mask    = (const float*)d_in[3];  // [B,L]
    const float* W       = (const float*)d_in[4];  // [ATT,RNN]
    const float* b_h2att = (const float*)d_in[5];  // [ATT]
    const float* w_alpha = (const float*)d_in[6];  // [ATT]
    const float* b_alpha = (const float*)d_in[7];  // [1]

    float* att_h  = (float*)d_ws;                       // B*ATT   = 65536
    float* dot    = att_h + (size_t)B_ * ATT_;          // B*L     = 131072
    float* weight = dot + (size_t)B_ * L_;              // B*L     = 131072
    float* out    = (float*)d_out;

    // K1: h @ W^T + bias
    k1_h2att<<<dim3(ATT_ / 64, B_ / 16), 256, 0, stream>>>(h, W, b_h2att, att_h);

    // K2: scores
    k2_score<<<(B_ * L_) / 4, 256, 0, stream>>>(f2, att_h, w_alpha, b_alpha, dot);

    // K3: masked softmax
    k3_softmax<<<B_, 256, 0, stream>>>(dot, mask, weight);

    // zero output (poisoned 0xAA before every call), then K4 accumulates
    hipMemsetAsync(out, 0, (size_t)out_size * sizeof(float), stream);
    k4_wsum<<<dim3(B_, 16), 256, 0, stream>>>(f1, weight, out);
}

// Round 2
// 870.733 us; speedup vs baseline: 1.0025x; 1.0025x over previous
//
#include <hip/hip_runtime.h>

// Problem constants (from reference): B=128, L=1024, RNN=1024, ATT=512
#define B_   128
#define L_   1024
#define RNN_ 1024
#define ATT_ 512

// ---------------------------------------------------------------------------
// fast tanh: tanh(x) = 1 - 2/(exp(2x)+1).  Abs err ~2e-7 << 4.6e-3 threshold.
__device__ __forceinline__ float fast_tanh(float x) {
    float e = __expf(2.0f * x);
    return 1.0f - __fdividef(2.0f, e + 1.0f);
}

// ---------------------------------------------------------------------------
// K1: att_h[b,a] = sum_k h[b,k] * W[a,k] + bias[a]
// Tiled GEMM: block tile 16(b) x 64(a), K-chunks of 64. 256 threads.
__global__ __launch_bounds__(256) void k1_h2att(
        const float* __restrict__ h, const float* __restrict__ W,
        const float* __restrict__ bias, float* __restrict__ att_h) {
    __shared__ float hs[16][64];
    __shared__ float ws[64][65];       // +1 pad: conflict-free compute reads
    const int a0 = blockIdx.x * 64;
    const int b0 = blockIdx.y * 16;
    const int t  = threadIdx.x;
    const int a_local = t & 63;
    const int brow    = (t >> 6) * 4;

    float acc[4] = {0.f, 0.f, 0.f, 0.f};

    for (int k0 = 0; k0 < RNN_; k0 += 64) {
        {
            int r = t >> 4, c = (t & 15) * 4;
            const float4 v = *(const float4*)&h[(size_t)(b0 + r) * RNN_ + k0 + c];
            hs[r][c + 0] = v.x; hs[r][c + 1] = v.y;
            hs[r][c + 2] = v.z; hs[r][c + 3] = v.w;
        }
        #pragma unroll
        for (int j = 0; j < 4; j++) {
            int r = (t >> 4) + 16 * j, c = (t & 15) * 4;
            const float4 v = *(const float4*)&W[(size_t)(a0 + r) * RNN_ + k0 + c];
            ws[r][c + 0] = v.x; ws[r][c + 1] = v.y;
            ws[r][c + 2] = v.z; ws[r][c + 3] = v.w;
        }
        __syncthreads();
        #pragma unroll 8
        for (int kk = 0; kk < 64; kk++) {
            const float wv = ws[a_local][kk];
            #pragma unroll
            for (int j = 0; j < 4; j++)
                acc[j] = fmaf(hs[brow + j][kk], wv, acc[j]);
        }
        __syncthreads();
    }
    const float bs = bias[a0 + a_local];
    #pragma unroll
    for (int j = 0; j < 4; j++)
        att_h[(size_t)(b0 + brow + j) * ATT_ + a0 + a_local] = acc[j] + bs;
}

// ---------------------------------------------------------------------------
// K2: dot[b,l] = sum_a tanh(f2[b,l,a] + att_h[b,a]) * w_alpha[a] + b_alpha
// One wave per TWO consecutive l's (reuses att_h/w_alpha regs, halves
// reduce overhead). 4 waves/block, 16384 blocks.
__global__ __launch_bounds__(256) void k2_score(
        const float* __restrict__ f2, const float* __restrict__ att_h,
        const float* __restrict__ w_alpha, const float* __restrict__ b_alpha,
        float* __restrict__ dot) {
    const int wid  = (blockIdx.x * 256 + threadIdx.x) >> 6;  // wave id = pair id
    const int lane = threadIdx.x & 63;
    const int b  = wid >> 9;           // 512 pairs per b
    const int l0 = (wid & 511) << 1;

    const float4* f  = (const float4*)f2 + (size_t)(b * L_ + l0) * (ATT_ / 4);
    const float4* ah = (const float4*)att_h + (size_t)b * (ATT_ / 4);
    const float4* wa = (const float4*)w_alpha;

    float s0 = 0.f, s1 = 0.f;
    #pragma unroll
    for (int i = 0; i < 2; i++) {
        const int idx = lane + i * 64;
        const float4 a = ah[idx];
        const float4 w = wa[idx];
        const float4 x = f[idx];            // row l0
        const float4 y = f[idx + ATT_ / 4]; // row l0+1
        s0 = fmaf(fast_tanh(x.x + a.x), w.x, s0);
        s0 = fmaf(fast_tanh(x.y + a.y), w.y, s0);
        s0 = fmaf(fast_tanh(x.z + a.z), w.z, s0);
        s0 = fmaf(fast_tanh(x.w + a.w), w.w, s0);
        s1 = fmaf(fast_tanh(y.x + a.x), w.x, s1);
        s1 = fmaf(fast_tanh(y.y + a.y), w.y, s1);
        s1 = fmaf(fast_tanh(y.z + a.z), w.z, s1);
        s1 = fmaf(fast_tanh(y.w + a.w), w.w, s1);
    }
    #pragma unroll
    for (int off = 32; off > 0; off >>= 1) {
        s0 += __shfl_xor(s0, off, 64);
        s1 += __shfl_xor(s1, off, 64);
    }
    if (lane == 0) {
        const float ba = b_alpha[0];
        dot[b * L_ + l0 + 0] = s0 + ba;
        dot[b * L_ + l0 + 1] = s1 + ba;
    }
}

// ---------------------------------------------------------------------------
// K3: per-b stats only: mx = max_l dot, s = sum_l exp(dot-mx)*mask.
// stats[b] = (mx, 1/s).  Softmax denom cancels against masked renorm:
// w_l = e_l * m_l / sum_k e_k * m_k.
__global__ __launch_bounds__(256) void k3_stats(
        const float* __restrict__ dot, const float* __restrict__ mask,
        float2* __restrict__ stats) {
    const int b = blockIdx.x, t = threadIdx.x;
    const int base = b * L_;
    const int wv = t >> 6, lane = t & 63;
    __shared__ float sred[4];

    float v[4];
    float mx = -3.4e38f;
    #pragma unroll
    for (int j = 0; j < 4; j++) {
        v[j] = dot[base + t + 256 * j];
        mx = fmaxf(mx, v[j]);
    }
    #pragma unroll
    for (int off = 32; off > 0; off >>= 1)
        mx = fmaxf(mx, __shfl_xor(mx, off, 64));
    if (lane == 0) sred[wv] = mx;
    __syncthreads();
    mx = fmaxf(fmaxf(sred[0], sred[1]), fmaxf(sred[2], sred[3]));
    __syncthreads();

    float s = 0.f;
    #pragma unroll
    for (int j = 0; j < 4; j++)
        s += __expf(v[j] - mx) * mask[base + t + 256 * j];
    #pragma unroll
    for (int off = 32; off > 0; off >>= 1)
        s += __shfl_xor(s, off, 64);
    if (lane == 0) sred[wv] = s;
    __syncthreads();
    if (t == 0) {
        const float stot = sred[0] + sred[1] + sred[2] + sred[3];
        stats[b] = make_float2(mx, 1.0f / stot);
    }
}

// ---------------------------------------------------------------------------
// K4: out[b,d] += sum_l w[b,l] * f1[b,l,d], w reconstructed from dot/mask/
// stats in LDS. Grid (B, 8): 1024 blocks, 128 l's each, 8-way atomics.
__global__ __launch_bounds__(256) void k4_wsum(
        const float* __restrict__ f1, const float* __restrict__ dot,
        const float* __restrict__ mask, const float2* __restrict__ stats,
        float* __restrict__ out) {
    const int b = blockIdx.x, lc = blockIdx.y, t = threadIdx.x;
    __shared__ float w[128];
    const float2 st = stats[b];  // (mx, inv_denom)
    const int lbase = b * L_ + lc * 128;
    if (t < 128)
        w[t] = __expf(dot[lbase + t] - st.x) * mask[lbase + t] * st.y;
    __syncthreads();

    const float4* base =
        (const float4*)f1 + ((size_t)b * L_ + lc * 128) * (RNN_ / 4) + t;

    float4 acc = make_float4(0.f, 0.f, 0.f, 0.f);
    #pragma unroll 8
    for (int l = 0; l < 128; l++) {
        const float wv = w[l];                       // wave-uniform: broadcast
        const float4 x = base[(size_t)l * (RNN_ / 4)];
        acc.x = fmaf(wv, x.x, acc.x);
        acc.y = fmaf(wv, x.y, acc.y);
        acc.z = fmaf(wv, x.z, acc.z);
        acc.w = fmaf(wv, x.w, acc.w);
    }
    float* o = out + b * RNN_ + t * 4;
    atomicAdd(o + 0, acc.x);
    atomicAdd(o + 1, acc.y);
    atomicAdd(o + 2, acc.z);
    atomicAdd(o + 3, acc.w);
}

// ---------------------------------------------------------------------------
extern "C" void kernel_launch(void* const* d_in, const int* in_sizes, int n_in,
                              void* d_out, int out_size, void* d_ws, size_t ws_size,
                              hipStream_t stream) {
    const float* h       = (const float*)d_in[0];
    const float* f1      = (const float*)d_in[1];  // [B,L,RNN]
    const float* f2      = (const float*)d_in[2];  // [B,L,ATT]
    const float* mask    = (const float*)d_in[3];  // [B,L]
    const float* W       = (const float*)d_in[4];  // [ATT,RNN]
    const float* b_h2att = (const float*)d_in[5];  // [ATT]
    const float* w_alpha = (const float*)d_in[6];  // [ATT]
    const float* b_alpha = (const float*)d_in[7];  // [1]

    float*  att_h = (float*)d_ws;                      // B*ATT = 65536 floats
    float*  dot   = att_h + (size_t)B_ * ATT_;         // B*L   = 131072 floats
    float2* stats = (float2*)(dot + (size_t)B_ * L_);  // B float2
    float*  out   = (float*)d_out;

    k1_h2att<<<dim3(ATT_ / 64, B_ / 16), 256, 0, stream>>>(h, W, b_h2att, att_h);
    k2_score<<<(B_ * L_ / 2) / 4, 256, 0, stream>>>(f2, att_h, w_alpha, b_alpha, dot);
    k3_stats<<<B_, 256, 0, stream>>>(dot, mask, stats);
    hipMemsetAsync(out, 0, (size_t)out_size * sizeof(float), stream);
    k4_wsum<<<dim3(B_, 8), 256, 0, stream>>>(f1, dot, mask, stats, out);
}